// Round 4
// baseline (136.625 us; speedup 1.0000x reference)
//
#include <hip/hip_runtime.h>

#define BB 16
#define CC 2
#define TT 1000
#define FF 257
#define NCHAIN (BB * CC * FF)                       // 8224
#define RES_ELEMS ((size_t)BB * CC * TT * FF * 2)   // 16,448,000

#define CPB 16          // chains per block (== threadIdx.x extent)
#define KCH 32          // chunks per chain
#define LCH 32          // timesteps per chunk (32*32 = 1024 >= 1000, tail predicated)

// block = (16, 32) = 512 threads = 8 waves; grid = 8224/16 = 514 blocks.
// launch_bounds(512, 4): cap 128 unified regs/wave (round 3 proved the x[32]
// buffer lives in AGPRs at this budget with NO load remat) -> 4 waves/SIMD ->
// 16 waves/CU -> 2 blocks/CU resident. 514 blocks = 512 concurrent + 2
// backfilled -> no serial straggler tail (round-3 failure mode: grid 257 = 1
// block/CU + 1 block running ALONE for the second half of the kernel).
__global__ __launch_bounds__(512, 4) void fnorm_kernel(
    const float* __restrict__ input,
    const float* __restrict__ weights,
    const float* __restrict__ bias,
    const float* __restrict__ alpha,
    const float* __restrict__ s1,
    float* __restrict__ out)
{
    const int tx = threadIdx.x;          // chain within block (0..15)
    const int k  = threadIdx.y;          // chunk index (0..31)
    const int chain = blockIdx.x * CPB + tx;   // 514*16 = 8224 exact

    const int f  = chain % FF;
    const int bc = chain / FF;
    const int c  = bc % CC;
    const int cf = c * FF + f;

    const float2* __restrict__ in2 = (const float2*)input + (size_t)bc * (TT * FF) + f;
    float2* __restrict__ out2      = (float2*)out        + (size_t)bc * (TT * FF) + f;

    const float av = 1.0f / (1.0f + __expf(-alpha[cf]));
    const float om = 1.0f - av;
    const float w  = weights[cf];
    const float bi = bias[cf];

    const int t0  = k * LCH;
    const int rem = TT - t0;                                 // >= 8 always
    const int n   = rem < LCH ? rem : LCH;

    // Phase A: load chunk into registers (AGPR-backed buffer). A 16-lane row
    // (fixed k) covers 16 consecutive chains -> 128 B contiguous segments.
    float2 x[LCH];
    #pragma unroll
    for (int t = 0; t < LCH; ++t)
        if (t < n) x[t] = in2[(size_t)(t0 + t) * FF];

    float s = 0.0f;
    float p = 1.0f;
    #pragma unroll
    for (int t = 0; t < LCH; ++t) {
        if (t < n) {
            float2 v = x[t];
            float d2 = fmaf(v.x, v.x, v.y * v.y);
            s = fmaf(d2, av, s * om);
            p *= om;
        }
    }

    // Fix-up: wave-parallel affine scan over chunks. 512 threads = 16 groups
    // of 32 lanes; group g owns chain g, lane-within-group = chunk.
    // Compose affine maps S -> p*S + e with a width-32 shuffle scan.
    __shared__ float p_s[KCH][CPB + 1];   // stride 17: gcd(17,32)=1, conflict-free
    __shared__ float e_s[KCH][CPB + 1];
    __shared__ float i_s[KCH][CPB + 1];
    p_s[k][tx] = p;
    e_s[k][tx] = s;
    __syncthreads();
    {
        const int tid = tx + k * CPB;
        const int ch  = tid >> 5;                     // chain 0..15 (uniform per half-wave)
        const int ck  = tid & 31;                     // chunk 0..31 == lane&31
        float pp = p_s[ck][ch];
        float ee = e_s[ck][ch];
        #pragma unroll
        for (int d = 1; d < 32; d <<= 1) {
            float pu = __shfl_up(pp, d, 32);
            float eu = __shfl_up(ee, d, 32);
            if (ck >= d) { ee = fmaf(pp, eu, ee); pp *= pu; }
        }
        const float S0 = s1[blockIdx.x * CPB + ch];
        float Sin = fmaf(pp, S0, ee);          // inclusive state after chunk ck
        float Sex = __shfl_up(Sin, 1, 32);     // exclusive = init state for chunk ck
        if (ck == 0) Sex = S0;
        i_s[ck][ch] = Sex;
        if (ck == KCH - 1)
            out[RES_ELEMS + (size_t)(blockIdx.x * CPB + ch)] = Sin;  // s_last
    }
    __syncthreads();

    // Phase B: rescan chunk from registers with correct initial state.
    s = i_s[k][tx];
    #pragma unroll
    for (int t = 0; t < LCH; ++t) {
        if (t < n) {
            float2 v = x[t];
            float d2 = fmaf(v.x, v.x, v.y * v.y);
            s = fmaf(d2, av, s * om);
            float inv = __frsqrt_rn(s + 1e-16f) * w;
            float2 y;
            y.x = fmaf(v.x, inv, bi);
            y.y = fmaf(v.y, inv, bi);
            out2[(size_t)(t0 + t) * FF] = y;
        }
    }
}

extern "C" void kernel_launch(void* const* d_in, const int* in_sizes, int n_in,
                              void* d_out, int out_size, void* d_ws, size_t ws_size,
                              hipStream_t stream) {
    const float* input   = (const float*)d_in[0];
    const float* weights = (const float*)d_in[1];
    const float* bias    = (const float*)d_in[2];
    const float* alpha   = (const float*)d_in[3];
    const float* s1      = (const float*)d_in[4];
    float* out = (float*)d_out;

    dim3 block(CPB, KCH);               // 512 threads = 8 waves
    dim3 grid(NCHAIN / CPB);            // 514 blocks
    hipLaunchKernelGGL(fnorm_kernel, grid, block, 0, stream,
                       input, weights, bias, alpha, s1, out);
}